// Round 4
// baseline (217.138 us; speedup 1.0000x reference)
//
#include <hip/hip_runtime.h>

typedef __attribute__((ext_vector_type(8))) short short8;
typedef __attribute__((ext_vector_type(4))) float f32x4;
typedef unsigned short u16;

#define BB 4
#define TT 4096
#define CC 1024
#define HH 64

static __device__ __forceinline__ u16 f2bf(float f) {
    unsigned int u = __float_as_uint(f);
    unsigned int r = (u + 0x7FFFu + ((u >> 16) & 1u)) >> 16;  // RNE
    return (u16)r;
}

// LDS tile addressing: 64-u16 rows, 8 chunks of 8 u16 (16B); chunk XOR-swizzled by row&7.
static __device__ __forceinline__ int swz(int row, int chunk) {
    return row * 64 + ((chunk ^ (row & 7)) << 3);
}

// ---------------- dtype probe: flag=1 -> bf16 buffers, flag=0 -> f32 buffers.
__global__ void detect_dtype(const u16* __restrict__ xu, int* __restrict__ flag) {
    int lane = threadIdx.x;
    int cnt = 0;
    for (int i = lane; i < 1024; i += 64) {
        u16 u = xu[2 * i];
        int e = (u >> 7) & 0xFF;
        cnt += (e >= 100 && e <= 140) ? 1 : 0;
    }
    for (int d = 1; d < 64; d <<= 1) cnt += __shfl_xor(cnt, d);
    if (lane == 0) *flag = (cnt > 512) ? 1 : 0;
}

// ---------------- W -> Wt[192][1024] bf16 (rows: 0-63 q, 64-127 k, 128-191 v)
__global__ void wt_transpose(const void* __restrict__ Wk, const void* __restrict__ Wq,
                             const void* __restrict__ Wv, u16* __restrict__ Wt,
                             const int* __restrict__ flag) {
    const int isbf = *flag;
    int r = blockIdx.x;
    int w = r >> 6;
    int n = r & 63;
    const void* W = (w == 0) ? Wq : (w == 1) ? Wk : Wv;
    int k0 = threadIdx.x * 4;
    ushort4 v;
    if (isbf) {
        const u16* Wb = (const u16*)W;
        v.x = Wb[(k0 + 0) * HH + n]; v.y = Wb[(k0 + 1) * HH + n];
        v.z = Wb[(k0 + 2) * HH + n]; v.w = Wb[(k0 + 3) * HH + n];
    } else {
        const float* Wf = (const float*)W;
        v.x = f2bf(Wf[(k0 + 0) * HH + n]); v.y = f2bf(Wf[(k0 + 1) * HH + n]);
        v.z = f2bf(Wf[(k0 + 2) * HH + n]); v.w = f2bf(Wf[(k0 + 3) * HH + n]);
    }
    *reinterpret_cast<ushort4*>(Wt + (size_t)r * CC + k0) = v;
}

// ---------------- zero a float region (grid-stride float4)
__global__ void zero_f4(float* __restrict__ p, int n4) {
    float4 z = {0.f, 0.f, 0.f, 0.f};
    for (int i = blockIdx.x * blockDim.x + threadIdx.x; i < n4; i += gridDim.x * blockDim.x)
        reinterpret_cast<float4*>(p)[i] = z;
}

// ---------------- QKV projection, register-prefetched staging
__global__ __launch_bounds__(256) void qkv_proj(const void* __restrict__ x, const u16* __restrict__ Wt,
                                                u16* __restrict__ qo, u16* __restrict__ ko,
                                                u16* __restrict__ vo, const int* __restrict__ flag) {
    __shared__ __align__(16) u16 xs[64 * 64];
    __shared__ __align__(16) u16 ws[192 * 64];
    const int isbf = *flag;
    const int tid = threadIdx.x;
    const int lane = tid & 63;
    const int w = tid >> 6;
    const int l15 = lane & 15;
    const int quad = lane >> 4;
    const int mb = blockIdx.x;

    f32x4 zero = {0.f, 0.f, 0.f, 0.f};
    f32x4 acc[12];
    #pragma unroll
    for (int i = 0; i < 12; i++) acc[i] = zero;

    // prefetch registers (one kb tile ahead)
    float4 pxf[2][2];
    uint4  pxb[2];
    uint4  pw[6];

    auto prefetch = [&](int kb) {
        #pragma unroll
        for (int j = 0; j < 2; j++) {
            int cc = tid + j * 256;
            int row = cc >> 3, c8 = cc & 7;
            size_t src = (size_t)(mb * 64 + row) * CC + kb * 64 + c8 * 8;
            if (isbf) {
                pxb[j] = *reinterpret_cast<const uint4*>((const u16*)x + src);
            } else {
                const float4* p = reinterpret_cast<const float4*>((const float*)x + src);
                pxf[j][0] = p[0]; pxf[j][1] = p[1];
            }
        }
        #pragma unroll
        for (int j = 0; j < 6; j++) {
            int cc = tid + j * 256;
            int row = cc >> 3, c8 = cc & 7;
            pw[j] = *reinterpret_cast<const uint4*>(Wt + (size_t)row * CC + kb * 64 + c8 * 8);
        }
    };
    auto commit = [&]() {
        #pragma unroll
        for (int j = 0; j < 2; j++) {
            int cc = tid + j * 256;
            int row = cc >> 3, c8 = cc & 7;
            int dst = swz(row, c8);
            if (isbf) {
                *reinterpret_cast<uint4*>(xs + dst) = pxb[j];
            } else {
                float4 a0 = pxf[j][0], a1 = pxf[j][1];
                ushort4 lo; lo.x = f2bf(a0.x); lo.y = f2bf(a0.y); lo.z = f2bf(a0.z); lo.w = f2bf(a0.w);
                ushort4 hi; hi.x = f2bf(a1.x); hi.y = f2bf(a1.y); hi.z = f2bf(a1.z); hi.w = f2bf(a1.w);
                *reinterpret_cast<ushort4*>(xs + dst) = lo;
                *reinterpret_cast<ushort4*>(xs + dst + 4) = hi;
            }
        }
        #pragma unroll
        for (int j = 0; j < 6; j++) {
            int cc = tid + j * 256;
            int row = cc >> 3, c8 = cc & 7;
            *reinterpret_cast<uint4*>(ws + swz(row, c8)) = pw[j];
        }
    };

    prefetch(0);
    for (int kb = 0; kb < 16; kb++) {
        commit();
        if (kb < 15) prefetch(kb + 1);
        __syncthreads();
        #pragma unroll
        for (int k2 = 0; k2 < 2; k2++) {
            short8 af = *reinterpret_cast<const short8*>(xs + swz(w * 16 + l15, k2 * 4 + quad));
            #pragma unroll
            for (int nt = 0; nt < 12; nt++) {
                short8 bf = *reinterpret_cast<const short8*>(ws + swz(nt * 16 + l15, k2 * 4 + quad));
                acc[nt] = __builtin_amdgcn_mfma_f32_16x16x32_bf16(af, bf, acc[nt], 0, 0, 0);
            }
        }
        __syncthreads();
    }

    const float qscale = 0.18033688011112042f;      // log2(e)/8
    const int g0 = mb * 64 + w * 16 + quad * 4;
    #pragma unroll
    for (int nt = 0; nt < 12; nt++) {
        const int p = nt >> 2;
        const int h = (nt & 3) * 16 + l15;
        #pragma unroll
        for (int r = 0; r < 4; r++) {
            int g = g0 + r;
            float v = acc[nt][r];
            if (p == 0)      qo[(size_t)g * HH + h] = f2bf(v * qscale);
            else if (p == 1) ko[(size_t)g * HH + h] = f2bf(v);
            else {
                int b = g >> 12, t = g & 4095;
                vo[((size_t)(b * HH + h)) * TT + t] = f2bf(v);
            }
        }
    }
}

// ---------------- causal flash attention, split-K over key tiles
// grid = BB*128*nsplit blocks x 128 threads. Single-buffered LDS (20.5 KB).
// Fixed-max softmax (log2 domain, |s|<~4) => partials are linear; split blocks
// atomicAdd f32 partial (o, l) into ws accumulators; finalize normalizes.
__global__ __launch_bounds__(128) void attn(const u16* __restrict__ qp, const u16* __restrict__ kp,
                                            const u16* __restrict__ vp, float* __restrict__ acco,
                                            float* __restrict__ accl, void* __restrict__ outv,
                                            const int* __restrict__ flag, int nsplit) {
    __shared__ __align__(16) u16 kst[64 * 64];   // (key, h), swizzled
    __shared__ __align__(16) u16 vts[64 * 64];   // (h, key), swizzled
    __shared__ __align__(16) u16 pb[2][16 * 64]; // per-wave P, (qrow, key), swizzled
    const int isbf = *flag;
    const int tid = threadIdx.x;
    const int lane = tid & 63;
    const int w = tid >> 6;
    const int l15 = lane & 15;
    const int quad = lane >> 4;

    int u = blockIdx.x;
    int b, qt, ks;
    if (nsplit == 1) {
        b = u >> 7;
        int raw = u & 127;
        qt = (raw & 1) ? (127 - (raw >> 1)) : (raw >> 1);   // tail balance
        ks = 0;
    } else {
        int per = 128 * nsplit;
        b = u / per;
        int rem = u - b * per;
        qt = rem / nsplit;
        ks = rem - qt * nsplit;
    }
    int qbase = qt * 32;
    int diag = qbase >> 6;
    int nkt = diag + 1;
    if (ks >= nkt) return;            // empty split (block-uniform)

    short8 aq[2];
    {
        const u16* qrow = qp + (size_t)(b * TT + qbase + w * 16 + l15) * HH;
        aq[0] = *reinterpret_cast<const short8*>(qrow + quad * 8);
        aq[1] = *reinterpret_cast<const short8*>(qrow + 32 + quad * 8);
    }

    f32x4 zero = {0.f, 0.f, 0.f, 0.f};
    f32x4 o[4];
    #pragma unroll
    for (int i = 0; i < 4; i++) o[i] = zero;
    f32x4 lsum = zero;

    auto stage = [&](int kt2) {
        #pragma unroll
        for (int j = 0; j < 4; j++) {
            int cc = tid + j * 128;
            int row = cc >> 3, c8 = cc & 7;
            int dst = swz(row, c8);
            uint4 dk = *reinterpret_cast<const uint4*>(kp + (size_t)(b * TT + kt2 * 64 + row) * HH + c8 * 8);
            *reinterpret_cast<uint4*>(&kst[dst]) = dk;
            uint4 dv = *reinterpret_cast<const uint4*>(vp + ((size_t)(b * HH + row)) * TT + kt2 * 64 + c8 * 8);
            *reinterpret_cast<uint4*>(&vts[dst]) = dv;
        }
    };

    for (int kt = ks; kt < nkt; kt += nsplit) {
        __syncthreads();              // previous iter's LDS reads done
        stage(kt);
        __syncthreads();              // staging visible
        // S = Q K^T (log2 domain)
        f32x4 s[4];
        #pragma unroll
        for (int i = 0; i < 4; i++) s[i] = zero;
        #pragma unroll
        for (int k2 = 0; k2 < 2; k2++) {
            #pragma unroll
            for (int nt = 0; nt < 4; nt++) {
                short8 bf = *reinterpret_cast<const short8*>(&kst[swz(nt * 16 + l15, k2 * 4 + quad)]);
                s[nt] = __builtin_amdgcn_mfma_f32_16x16x32_bf16(aq[k2], bf, s[nt], 0, 0, 0);
            }
        }
        // p = exp2(s), causal mask on diagonal tile
        const int rg = qbase + w * 16 + quad * 4;
        const bool dm = (kt == diag);
        #pragma unroll
        for (int nt = 0; nt < 4; nt++) {
            int key = kt * 64 + nt * 16 + l15;
            #pragma unroll
            for (int r = 0; r < 4; r++) {
                float p = __builtin_amdgcn_exp2f(s[nt][r]);
                if (dm && key > rg + r) p = 0.f;
                s[nt][r] = p;
            }
        }
        #pragma unroll
        for (int nt = 0; nt < 4; nt++) lsum = lsum + s[nt];
        // P (C/D layout) -> per-wave LDS A-layout (same-wave RAW; no barrier needed)
        #pragma unroll
        for (int nt = 0; nt < 4; nt++) {
            int chunk = nt * 2 + (l15 >> 3);
            int off = l15 & 7;
            #pragma unroll
            for (int r = 0; r < 4; r++) {
                int row = quad * 4 + r;
                pb[w][row * 64 + ((chunk ^ (row & 7)) << 3) + off] = f2bf(s[nt][r]);
            }
        }
        // O += P V
        #pragma unroll
        for (int k2 = 0; k2 < 2; k2++) {
            short8 ap = *reinterpret_cast<const short8*>(&pb[w][swz(l15, k2 * 4 + quad)]);
            #pragma unroll
            for (int nt = 0; nt < 4; nt++) {
                short8 bv = *reinterpret_cast<const short8*>(&vts[swz(nt * 16 + l15, k2 * 4 + quad)]);
                o[nt] = __builtin_amdgcn_mfma_f32_16x16x32_bf16(ap, bv, o[nt], 0, 0, 0);
            }
        }
    }

    // reduce lsum across the 16 lanes holding each row's columns
    #pragma unroll
    for (int d = 1; d < 16; d <<= 1) {
        f32x4 t;
        #pragma unroll
        for (int r = 0; r < 4; r++) t[r] = __shfl_xor(lsum[r], d);
        lsum = lsum + t;
    }
    const int g0 = b * TT + qbase + w * 16 + quad * 4;

    if (nsplit == 1) {
        f32x4 inv;
        #pragma unroll
        for (int r = 0; r < 4; r++) inv[r] = 1.0f / lsum[r];
        if (isbf) {
            u16* outp = (u16*)outv;
            #pragma unroll
            for (int nt = 0; nt < 4; nt++)
                #pragma unroll
                for (int r = 0; r < 4; r++)
                    outp[(size_t)(g0 + r) * HH + nt * 16 + l15] = f2bf(o[nt][r] * inv[r]);
        } else {
            float* outp = (float*)outv;
            #pragma unroll
            for (int nt = 0; nt < 4; nt++)
                #pragma unroll
                for (int r = 0; r < 4; r++)
                    outp[(size_t)(g0 + r) * HH + nt * 16 + l15] = o[nt][r] * inv[r];
        }
    } else {
        #pragma unroll
        for (int nt = 0; nt < 4; nt++)
            #pragma unroll
            for (int r = 0; r < 4; r++)
                atomicAdd(&acco[(size_t)(g0 + r) * HH + nt * 16 + l15], o[nt][r]);
        if (l15 == 0) {
            #pragma unroll
            for (int r = 0; r < 4; r++) atomicAdd(&accl[g0 + r], lsum[r]);
        }
    }
}

// ---------------- finalize: out = acco / accl (row-broadcast), dtype per flag
__global__ __launch_bounds__(256) void attn_finalize(const float* __restrict__ acco,
                                                     const float* __restrict__ accl,
                                                     void* __restrict__ outv,
                                                     const int* __restrict__ flag) {
    const int isbf = *flag;
    int i = blockIdx.x * blockDim.x + threadIdx.x;   // 262144 float4 groups
    int row = i >> 4;                                // 16 groups per 64-col row
    float4 ov = reinterpret_cast<const float4*>(acco)[i];
    float inv = 1.0f / accl[row];
    if (isbf) {
        ushort4 s;
        s.x = f2bf(ov.x * inv); s.y = f2bf(ov.y * inv);
        s.z = f2bf(ov.z * inv); s.w = f2bf(ov.w * inv);
        reinterpret_cast<ushort4*>(outv)[i] = s;
    } else {
        float4 s = {ov.x * inv, ov.y * inv, ov.z * inv, ov.w * inv};
        reinterpret_cast<float4*>(outv)[i] = s;
    }
}

extern "C" void kernel_launch(void* const* d_in, const int* in_sizes, int n_in,
                              void* d_out, int out_size, void* d_ws, size_t ws_size,
                              hipStream_t stream) {
    const void* x  = d_in[0];
    const void* Wk = d_in[1];
    const void* Wq = d_in[2];
    const void* Wv = d_in[3];
    char* ws = (char*)d_ws;
    // ws: qo 2MB | ko 2MB | vo 2MB | Wt 384KB @6M | flag @6.75M | acco 4MB @7M | accl 64KB @11M
    u16* qo = (u16*)(ws);
    u16* ko = (u16*)(ws + (size_t)2 * 1024 * 1024);
    u16* vo = (u16*)(ws + (size_t)4 * 1024 * 1024);
    u16* Wt = (u16*)(ws + (size_t)6 * 1024 * 1024);
    int* flag = (int*)(ws + (size_t)6 * 1024 * 1024 + 768 * 1024);
    float* acco = (float*)(ws + (size_t)7 * 1024 * 1024);
    float* accl = (float*)(ws + (size_t)11 * 1024 * 1024);

    const size_t need = (size_t)11 * 1024 * 1024 + 128 * 1024;
    const int nsplit = (ws_size >= need) ? 4 : 1;

    detect_dtype<<<1, 64, 0, stream>>>((const u16*)x, flag);
    wt_transpose<<<192, 256, 0, stream>>>(Wk, Wq, Wv, Wt, flag);
    qkv_proj<<<256, 256, 0, stream>>>(x, Wt, qo, ko, vo, flag);
    if (nsplit > 1) {
        zero_f4<<<520, 256, 0, stream>>>(acco, (4 * TT * HH + 4 * TT) / 4);  // acco+accl contiguous
        attn<<<BB * 128 * nsplit, 128, 0, stream>>>(qo, ko, vo, acco, accl, d_out, flag, nsplit);
        attn_finalize<<<(BB * TT * HH / 4) / 256, 256, 0, stream>>>(acco, accl, d_out, flag);
    } else {
        attn<<<BB * 128, 128, 0, stream>>>(qo, ko, vo, acco, accl, d_out, flag, 1);
    }
}

// Round 5
// 196.241 us; speedup vs baseline: 1.1065x; 1.1065x over previous
//
#include <hip/hip_runtime.h>

typedef __attribute__((ext_vector_type(8))) short short8;
typedef __attribute__((ext_vector_type(4))) float f32x4;
typedef unsigned short u16;

#define BB 4
#define TT 4096
#define CC 1024
#define HH 64

static __device__ __forceinline__ u16 f2bf(float f) {
    unsigned int u = __float_as_uint(f);
    unsigned int r = (u + 0x7FFFu + ((u >> 16) & 1u)) >> 16;  // RNE
    return (u16)r;
}

// LDS tile addressing for attn: 64-u16 rows, 8 chunks of 8 u16; chunk XOR-swizzled by row&7.
static __device__ __forceinline__ int swz(int row, int chunk) {
    return row * 64 + ((chunk ^ (row & 7)) << 3);
}

// ---------------- dtype probe: flag=1 -> bf16 buffers, flag=0 -> f32 buffers.
__global__ void detect_dtype(const u16* __restrict__ xu, int* __restrict__ flag) {
    int lane = threadIdx.x;
    int cnt = 0;
    for (int i = lane; i < 1024; i += 64) {
        u16 u = xu[2 * i];
        int e = (u >> 7) & 0xFF;
        cnt += (e >= 100 && e <= 140) ? 1 : 0;
    }
    for (int d = 1; d < 64; d <<= 1) cnt += __shfl_xor(cnt, d);
    if (lane == 0) *flag = (cnt > 512) ? 1 : 0;
}

// ---------------- W -> Wt[192][1024] bf16 (rows 0-63 q, 64-127 k, 128-191 v); blocks >=192 zero acc
__global__ void wt_transpose(const void* __restrict__ Wk, const void* __restrict__ Wq,
                             const void* __restrict__ Wv, u16* __restrict__ Wt,
                             float* __restrict__ accz, const int* __restrict__ flag) {
    if (blockIdx.x >= 192) {
        int zb = blockIdx.x - 192;
        const int n4 = (BB * TT * HH + BB * TT) / 4;   // acco + accl contiguous floats
        float4 z = {0.f, 0.f, 0.f, 0.f};
        for (int i = zb * 256 + threadIdx.x; i < n4; i += 256 * 256)
            reinterpret_cast<float4*>(accz)[i] = z;
        return;
    }
    const int isbf = *flag;
    int r = blockIdx.x;
    int w = r >> 6;
    int n = r & 63;
    const void* W = (w == 0) ? Wq : (w == 1) ? Wk : Wv;
    int k0 = threadIdx.x * 4;
    ushort4 v;
    if (isbf) {
        const u16* Wb = (const u16*)W;
        v.x = Wb[(k0 + 0) * HH + n]; v.y = Wb[(k0 + 1) * HH + n];
        v.z = Wb[(k0 + 2) * HH + n]; v.w = Wb[(k0 + 3) * HH + n];
    } else {
        const float* Wf = (const float*)W;
        v.x = f2bf(Wf[(k0 + 0) * HH + n]); v.y = f2bf(Wf[(k0 + 1) * HH + n]);
        v.z = f2bf(Wf[(k0 + 2) * HH + n]); v.w = f2bf(Wf[(k0 + 3) * HH + n]);
    }
    *reinterpret_cast<ushort4*>(Wt + (size_t)r * CC + k0) = v;
}

// ---------------- QKV projection: barrier-free, LDS-free main loop.
// 2048 blocks x 64 threads. Block = 1 wave: 16 rows (rowblk) x 96 cols (half).
// A-frags direct from x (bf16 or f32->bf16), B-frags direct from Wt (L2-resident).
__global__ __launch_bounds__(64) void qkv_proj(const void* __restrict__ x, const u16* __restrict__ Wt,
                                               u16* __restrict__ qo, u16* __restrict__ ko,
                                               u16* __restrict__ vo, const int* __restrict__ flag) {
    __shared__ __align__(16) u16 tls[16 * 32];   // epilogue transpose tile (1 wave/block)
    const int isbf = *flag;
    const int lane = threadIdx.x;
    const int l15 = lane & 15;
    const int quad = lane >> 4;
    const int u = blockIdx.x;
    const int rowblk = u >> 1;        // 0..1023 (16 rows each)
    const int half = u & 1;           // cols half*96 .. +96
    const int g0r = rowblk * 16;

    f32x4 zero = {0.f, 0.f, 0.f, 0.f};
    f32x4 acc[6];
    #pragma unroll
    for (int i = 0; i < 6; i++) acc[i] = zero;

    const u16* xb = (const u16*)x;
    const float* xf = (const float*)x;

    for (int kb = 0; kb < 16; kb++) {
        short8 af[2];
        #pragma unroll
        for (int k2 = 0; k2 < 2; k2++) {
            size_t src = (size_t)(g0r + l15) * CC + kb * 64 + k2 * 32 + quad * 8;
            if (isbf) {
                af[k2] = *reinterpret_cast<const short8*>(xb + src);
            } else {
                const float4* p = reinterpret_cast<const float4*>(xf + src);
                float4 a0 = p[0], a1 = p[1];
                short8 t;
                t[0] = (short)f2bf(a0.x); t[1] = (short)f2bf(a0.y);
                t[2] = (short)f2bf(a0.z); t[3] = (short)f2bf(a0.w);
                t[4] = (short)f2bf(a1.x); t[5] = (short)f2bf(a1.y);
                t[6] = (short)f2bf(a1.z); t[7] = (short)f2bf(a1.w);
                af[k2] = t;
            }
        }
        #pragma unroll
        for (int k2 = 0; k2 < 2; k2++) {
            #pragma unroll
            for (int ntl = 0; ntl < 6; ntl++) {
                int n = half * 96 + ntl * 16 + l15;
                short8 bf = *reinterpret_cast<const short8*>(Wt + (size_t)n * CC + kb * 64 + k2 * 32 + quad * 8);
                acc[ntl] = __builtin_amdgcn_mfma_f32_16x16x32_bf16(af[k2], bf, acc[ntl], 0, 0, 0);
            }
        }
    }

    // Epilogue: 3 pairs of 16-col tiles -> LDS transpose -> coalesced 16B stores.
    const float qscale = 0.18033688011112042f;   // log2(e)/8
    #pragma unroll
    for (int p2 = 0; p2 < 3; p2++) {
        int ntg0 = half * 6 + p2 * 2;
        bool isv = (ntg0 >= 8);
        bool isq = (ntg0 < 4);
        __syncthreads();
        if (!isv) {
            // layout [t(16)][c(32)]
            #pragma unroll
            for (int e = 0; e < 2; e++) {
                int ntl = p2 * 2 + e;
                float sc = isq ? qscale : 1.f;
                #pragma unroll
                for (int r = 0; r < 4; r++)
                    tls[(quad * 4 + r) * 32 + e * 16 + l15] = f2bf(acc[ntl][r] * sc);
            }
            __syncthreads();
            int t = lane & 15, seg = lane >> 4;
            ushort4 d0 = *reinterpret_cast<const ushort4*>(&tls[t * 32 + seg * 8]);
            ushort4 d1 = *reinterpret_cast<const ushort4*>(&tls[t * 32 + seg * 8 + 4]);
            u16* dst; int cb;
            if (isq) { dst = qo; cb = p2 * 32; }
            else     { dst = ko; cb = (half == 0) ? 0 : 32; }
            u16* pd = dst + (size_t)(g0r + t) * HH + cb + seg * 8;
            *reinterpret_cast<ushort4*>(pd) = d0;
            *reinterpret_cast<ushort4*>(pd + 4) = d1;
        } else {
            // v: layout [c(32)][t(16)] -> store along t into vo[b][h][t]
            #pragma unroll
            for (int e = 0; e < 2; e++) {
                int ntl = p2 * 2 + e;
                #pragma unroll
                for (int r = 0; r < 4; r++)
                    tls[(e * 16 + l15) * 16 + quad * 4 + r] = f2bf(acc[ntl][r]);
            }
            __syncthreads();
            int c = lane & 31, tseg = lane >> 5;
            ushort4 d0 = *reinterpret_cast<const ushort4*>(&tls[c * 16 + tseg * 8]);
            ushort4 d1 = *reinterpret_cast<const ushort4*>(&tls[c * 16 + tseg * 8 + 4]);
            int cb = (p2 - 1) * 32;
            int b = g0r >> 12, tb = g0r & 4095;
            u16* pd = vo + ((size_t)(b * HH + cb + c)) * TT + tb + tseg * 8;
            *reinterpret_cast<ushort4*>(pd) = d0;
            *reinterpret_cast<ushort4*>(pd + 4) = d1;
        }
    }
}

// ---------------- causal flash attention, 64 q-rows/block, split-K over 64-key tiles
// grid = BB*64*nsplit x 256 threads (4 waves). Single-buffered LDS.
__global__ __launch_bounds__(256) void attn(const u16* __restrict__ qp, const u16* __restrict__ kp,
                                            const u16* __restrict__ vp, float* __restrict__ acco,
                                            float* __restrict__ accl, void* __restrict__ outv,
                                            const int* __restrict__ flag, int nsplit) {
    __shared__ __align__(16) u16 kst[64 * 64];   // (key, h), swizzled
    __shared__ __align__(16) u16 vts[64 * 64];   // (h, key), swizzled
    __shared__ __align__(16) u16 pb[4][16 * 64]; // per-wave P
    const int isbf = *flag;
    const int tid = threadIdx.x;
    const int lane = tid & 63;
    const int w = tid >> 6;           // 0..3
    const int l15 = lane & 15;
    const int quad = lane >> 4;

    int u = blockIdx.x;
    int b, qt, ks;
    if (nsplit == 1) {
        b = u >> 6;
        int raw = u & 63;
        qt = (raw & 1) ? (63 - (raw >> 1)) : (raw >> 1);
        ks = 0;
    } else {
        int per = 64 * nsplit;
        b = u / per;
        int rem = u - b * per;
        qt = rem / nsplit;
        ks = rem - qt * nsplit;
    }
    int qbase = qt * 64;
    int diag = qt;
    int nkt = diag + 1;
    if (ks >= nkt) return;

    short8 aq[2];
    {
        const u16* qrow = qp + (size_t)(b * TT + qbase + w * 16 + l15) * HH;
        aq[0] = *reinterpret_cast<const short8*>(qrow + quad * 8);
        aq[1] = *reinterpret_cast<const short8*>(qrow + 32 + quad * 8);
    }

    f32x4 zero = {0.f, 0.f, 0.f, 0.f};
    f32x4 o[4];
    #pragma unroll
    for (int i = 0; i < 4; i++) o[i] = zero;
    f32x4 lsum = zero;

    for (int kt = ks; kt < nkt; kt += nsplit) {
        __syncthreads();              // previous iter's LDS reads done
        #pragma unroll
        for (int j = 0; j < 2; j++) {
            int cc = tid + j * 256;   // 512 chunks each
            int row = cc >> 3, c8 = cc & 7;
            int dst = swz(row, c8);
            uint4 dk = *reinterpret_cast<const uint4*>(kp + (size_t)(b * TT + kt * 64 + row) * HH + c8 * 8);
            *reinterpret_cast<uint4*>(&kst[dst]) = dk;
            uint4 dv = *reinterpret_cast<const uint4*>(vp + ((size_t)(b * HH + row)) * TT + kt * 64 + c8 * 8);
            *reinterpret_cast<uint4*>(&vts[dst]) = dv;
        }
        __syncthreads();              // staging visible
        // S = Q K^T (log2 domain via q pre-scale)
        f32x4 s[4];
        #pragma unroll
        for (int i = 0; i < 4; i++) s[i] = zero;
        #pragma unroll
        for (int k2 = 0; k2 < 2; k2++) {
            #pragma unroll
            for (int nt = 0; nt < 4; nt++) {
                short8 bf = *reinterpret_cast<const short8*>(&kst[swz(nt * 16 + l15, k2 * 4 + quad)]);
                s[nt] = __builtin_amdgcn_mfma_f32_16x16x32_bf16(aq[k2], bf, s[nt], 0, 0, 0);
            }
        }
        // p = exp2(s), causal mask on diagonal tile
        const int rg = qbase + w * 16 + quad * 4;
        const bool dm = (kt == diag);
        #pragma unroll
        for (int nt = 0; nt < 4; nt++) {
            int key = kt * 64 + nt * 16 + l15;
            #pragma unroll
            for (int r = 0; r < 4; r++) {
                float p = __builtin_amdgcn_exp2f(s[nt][r]);
                if (dm && key > rg + r) p = 0.f;
                s[nt][r] = p;
            }
        }
        #pragma unroll
        for (int nt = 0; nt < 4; nt++) lsum = lsum + s[nt];
        // P (C/D layout) -> per-wave LDS A-layout (same-wave RAW)
        #pragma unroll
        for (int nt = 0; nt < 4; nt++) {
            int chunk = nt * 2 + (l15 >> 3);
            int off = l15 & 7;
            #pragma unroll
            for (int r = 0; r < 4; r++) {
                int row = quad * 4 + r;
                pb[w][row * 64 + ((chunk ^ (row & 7)) << 3) + off] = f2bf(s[nt][r]);
            }
        }
        // O += P V
        #pragma unroll
        for (int k2 = 0; k2 < 2; k2++) {
            short8 ap = *reinterpret_cast<const short8*>(&pb[w][swz(l15, k2 * 4 + quad)]);
            #pragma unroll
            for (int nt = 0; nt < 4; nt++) {
                short8 bv = *reinterpret_cast<const short8*>(&vts[swz(nt * 16 + l15, k2 * 4 + quad)]);
                o[nt] = __builtin_amdgcn_mfma_f32_16x16x32_bf16(ap, bv, o[nt], 0, 0, 0);
            }
        }
    }

    #pragma unroll
    for (int d = 1; d < 16; d <<= 1) {
        f32x4 t;
        #pragma unroll
        for (int r = 0; r < 4; r++) t[r] = __shfl_xor(lsum[r], d);
        lsum = lsum + t;
    }
    const int g0 = b * TT + qbase + w * 16 + quad * 4;

    if (nsplit == 1) {
        f32x4 inv;
        #pragma unroll
        for (int r = 0; r < 4; r++) inv[r] = 1.0f / lsum[r];
        if (isbf) {
            u16* outp = (u16*)outv;
            #pragma unroll
            for (int nt = 0; nt < 4; nt++)
                #pragma unroll
                for (int r = 0; r < 4; r++)
                    outp[(size_t)(g0 + r) * HH + nt * 16 + l15] = f2bf(o[nt][r] * inv[r]);
        } else {
            float* outp = (float*)outv;
            #pragma unroll
            for (int nt = 0; nt < 4; nt++)
                #pragma unroll
                for (int r = 0; r < 4; r++)
                    outp[(size_t)(g0 + r) * HH + nt * 16 + l15] = o[nt][r] * inv[r];
        }
    } else {
        #pragma unroll
        for (int nt = 0; nt < 4; nt++)
            #pragma unroll
            for (int r = 0; r < 4; r++)
                atomicAdd(&acco[(size_t)(g0 + r) * HH + nt * 16 + l15], o[nt][r]);
        if (l15 == 0) {
            #pragma unroll
            for (int r = 0; r < 4; r++) atomicAdd(&accl[g0 + r], lsum[r]);
        }
    }
}

// ---------------- finalize: out = acco / accl
__global__ __launch_bounds__(256) void attn_finalize(const float* __restrict__ acco,
                                                     const float* __restrict__ accl,
                                                     void* __restrict__ outv,
                                                     const int* __restrict__ flag) {
    const int isbf = *flag;
    int i = blockIdx.x * blockDim.x + threadIdx.x;
    int row = i >> 4;
    float4 ov = reinterpret_cast<const float4*>(acco)[i];
    float inv = 1.0f / accl[row];
    if (isbf) {
        ushort4 s;
        s.x = f2bf(ov.x * inv); s.y = f2bf(ov.y * inv);
        s.z = f2bf(ov.z * inv); s.w = f2bf(ov.w * inv);
        reinterpret_cast<ushort4*>(outv)[i] = s;
    } else {
        float4 s = {ov.x * inv, ov.y * inv, ov.z * inv, ov.w * inv};
        reinterpret_cast<float4*>(outv)[i] = s;
    }
}

extern "C" void kernel_launch(void* const* d_in, const int* in_sizes, int n_in,
                              void* d_out, int out_size, void* d_ws, size_t ws_size,
                              hipStream_t stream) {
    const void* x  = d_in[0];
    const void* Wk = d_in[1];
    const void* Wq = d_in[2];
    const void* Wv = d_in[3];
    char* ws = (char*)d_ws;
    // ws: qo 2MB | ko 2MB | vo 2MB | Wt 384KB @6M | flag @6.75M | acco 4MB @7M | accl @11M
    u16* qo = (u16*)(ws);
    u16* ko = (u16*)(ws + (size_t)2 * 1024 * 1024);
    u16* vo = (u16*)(ws + (size_t)4 * 1024 * 1024);
    u16* Wt = (u16*)(ws + (size_t)6 * 1024 * 1024);
    int* flag = (int*)(ws + (size_t)6 * 1024 * 1024 + 768 * 1024);
    float* acco = (float*)(ws + (size_t)7 * 1024 * 1024);
    float* accl = (float*)(ws + (size_t)11 * 1024 * 1024);

    const size_t need = (size_t)11 * 1024 * 1024 + 128 * 1024;
    const int nsplit = (ws_size >= need) ? 4 : 1;

    detect_dtype<<<1, 64, 0, stream>>>((const u16*)x, flag);
    wt_transpose<<<(nsplit > 1 ? 448 : 192), 256, 0, stream>>>(Wk, Wq, Wv, Wt, acco, flag);
    qkv_proj<<<2048, 64, 0, stream>>>(x, Wt, qo, ko, vo, flag);
    if (nsplit > 1) {
        attn<<<BB * 64 * nsplit, 256, 0, stream>>>(qo, ko, vo, acco, accl, d_out, flag, nsplit);
        attn_finalize<<<(BB * TT * HH / 4) / 256, 256, 0, stream>>>(acco, accl, d_out, flag);
    } else {
        attn<<<BB * 64, 256, 0, stream>>>(qo, ko, vo, acco, accl, d_out, flag, 1);
    }
}

// Round 7
// 185.165 us; speedup vs baseline: 1.1727x; 1.0598x over previous
//
#include <hip/hip_runtime.h>

typedef __attribute__((ext_vector_type(8))) short short8;
typedef __attribute__((ext_vector_type(4))) float f32x4;
typedef unsigned short u16;

#define BB 4
#define TT 4096
#define CC 1024
#define HH 64

static __device__ __forceinline__ u16 f2bf(float f) {
    unsigned int u = __float_as_uint(f);
    unsigned int r = (u + 0x7FFFu + ((u >> 16) & 1u)) >> 16;  // RNE
    return (u16)r;
}

// attn LDS tile addressing: 64-u16 rows, 8 chunks of 8 u16; chunk XOR-swizzled by row&7.
static __device__ __forceinline__ int swz(int row, int chunk) {
    return row * 64 + ((chunk ^ (row & 7)) << 3);
}

// ---------------- dtype probe: flag=1 -> bf16 buffers, flag=0 -> f32 buffers.
__global__ void detect_dtype(const u16* __restrict__ xu, int* __restrict__ flag) {
    int lane = threadIdx.x;
    int cnt = 0;
    for (int i = lane; i < 1024; i += 64) {
        u16 u = xu[2 * i];
        int e = (u >> 7) & 0xFF;
        cnt += (e >= 100 && e <= 140) ? 1 : 0;
    }
    for (int d = 1; d < 64; d <<= 1) cnt += __shfl_xor(cnt, d);
    if (lane == 0) *flag = (cnt > 512) ? 1 : 0;
}

// ---------------- W -> Wtp packed B-fragment order; blocks >=192 zero acco/accl.
// Wtp 16B-chunk index: (((proj*4+nt)*16 + kb)*2 + k2)*64 + quad*16 + l15
// holding W[k = kb*64+k2*32+quad*8 .. +8][n = proj*64+nt*16+l15].
__global__ void wt_transpose(const void* __restrict__ Wk, const void* __restrict__ Wq,
                             const void* __restrict__ Wv, u16* __restrict__ Wtp,
                             float* __restrict__ accz, const int* __restrict__ flag) {
    if (blockIdx.x >= 192) {
        int zb = blockIdx.x - 192;
        const int n4 = (BB * TT * HH + BB * TT) / 4;   // acco + accl contiguous floats
        float4 z = {0.f, 0.f, 0.f, 0.f};
        for (int i = zb * 256 + threadIdx.x; i < n4; i += 256 * 256)
            reinterpret_cast<float4*>(accz)[i] = z;
        return;
    }
    const int isbf = *flag;
    int r = blockIdx.x;          // global output col 0..191
    int p = r >> 6;              // 0=q 1=k 2=v
    int n = r & 63;
    int nt = n >> 4, nl = n & 15;
    const void* W = (p == 0) ? Wq : (p == 1) ? Wk : Wv;
    int k0 = threadIdx.x * 4;    // 4 consecutive k per thread
    int kb = k0 >> 6, k2 = (k0 >> 5) & 1, quad = (k0 >> 3) & 3, half = (k0 >> 2) & 1;
    ushort4 v;
    if (isbf) {
        const u16* Wb = (const u16*)W;
        v.x = Wb[(k0 + 0) * HH + n]; v.y = Wb[(k0 + 1) * HH + n];
        v.z = Wb[(k0 + 2) * HH + n]; v.w = Wb[(k0 + 3) * HH + n];
    } else {
        const float* Wf = (const float*)W;
        v.x = f2bf(Wf[(k0 + 0) * HH + n]); v.y = f2bf(Wf[(k0 + 1) * HH + n]);
        v.z = f2bf(Wf[(k0 + 2) * HH + n]); v.w = f2bf(Wf[(k0 + 3) * HH + n]);
    }
    size_t off16 = ((size_t)((p * 4 + nt) * 16 + kb) * 2 + k2) * 64 + quad * 16 + nl;
    *reinterpret_cast<ushort4*>(Wtp + off16 * 8 + half * 4) = v;
}

// ---------------- xpack: x -> A-fragment order. Contiguous reads, 256B-strided 16B writes.
// dst 16B-chunk: (rb*32 + kb*2 + k2)*64 + quad*16 + l15  (rb = row/16).
__global__ __launch_bounds__(256) void xpack(const void* __restrict__ x, u16* __restrict__ xp,
                                             const int* __restrict__ flag) {
    const int isbf = *flag;
    #pragma unroll
    for (int j = 0; j < 4; j++) {
        int c = blockIdx.x * 1024 + j * 256 + threadIdx.x;   // 16B chunk id, 2M total
        int r = c >> 7, ck = c & 127;
        int kb = ck >> 3, rem = ck & 7;
        int k2 = rem >> 2, quad = rem & 3;
        int rb = r >> 4, l15 = r & 15;
        size_t dst = ((size_t)(rb * 32 + kb * 2 + k2) * 64 + quad * 16 + l15) * 8;
        if (isbf) {
            uint4 d = *reinterpret_cast<const uint4*>((const u16*)x + (size_t)c * 8);
            *reinterpret_cast<uint4*>(xp + dst) = d;
        } else {
            const float4* pf = reinterpret_cast<const float4*>((const float*)x + (size_t)c * 8);
            float4 a0 = pf[0], a1 = pf[1];
            ushort4 lo; lo.x = f2bf(a0.x); lo.y = f2bf(a0.y); lo.z = f2bf(a0.z); lo.w = f2bf(a0.w);
            ushort4 hi; hi.x = f2bf(a1.x); hi.y = f2bf(a1.y); hi.z = f2bf(a1.z); hi.w = f2bf(a1.w);
            *reinterpret_cast<ushort4*>(xp + dst) = lo;
            *reinterpret_cast<ushort4*>(xp + dst + 4) = hi;
        }
    }
}

// ---------------- QKV projection v3: 3072 blocks x 64 thr (1 wave).
// Block = (proj, 16-row group), XCD-affine. All global loads contiguous 1KB/instr.
__global__ __launch_bounds__(64) void qkv_proj(const void* __restrict__ x, const u16* __restrict__ xp,
                                               const u16* __restrict__ Wtp,
                                               u16* __restrict__ qo, u16* __restrict__ ko,
                                               u16* __restrict__ vo, const int* __restrict__ flag,
                                               int use_xp) {
    __shared__ __align__(16) u16 tls[16 * 32];
    const int isbf = *flag;
    const int lane = threadIdx.x;
    const int l15 = lane & 15;
    const int quad = lane >> 4;
    int phys = blockIdx.x;
    int xcd = phys & 7;
    int idx = phys >> 3;              // 0..383
    int proj = idx % 3;
    int rb = xcd * 128 + idx / 3;     // 0..1023
    const int g0r = rb * 16;

    f32x4 zero = {0.f, 0.f, 0.f, 0.f};
    f32x4 acc[4];
    #pragma unroll
    for (int i = 0; i < 4; i++) acc[i] = zero;

    const size_t bbase = (size_t)proj * 4 * 16 * 2 * 64 * 8;   // Wtp proj base (u16)

    if (use_xp) {
        short8 ac[2], an[2], bc[8], bn[8];
        auto loadf = [&](int kb, short8* a, short8* bfr) {
            #pragma unroll
            for (int k2 = 0; k2 < 2; k2++)
                a[k2] = *reinterpret_cast<const short8*>(xp + (((size_t)(rb * 32 + kb * 2 + k2) * 64 + lane) * 8));
            #pragma unroll
            for (int nt = 0; nt < 4; nt++)
                #pragma unroll
                for (int k2 = 0; k2 < 2; k2++)
                    bfr[nt * 2 + k2] = *reinterpret_cast<const short8*>(
                        Wtp + bbase + (((size_t)(nt * 16 + kb) * 2 + k2) * 64 + lane) * 8);
        };
        loadf(0, ac, bc);
        for (int kb = 0; kb < 16; kb++) {
            if (kb < 15) loadf(kb + 1, an, bn);
            #pragma unroll
            for (int k2 = 0; k2 < 2; k2++)
                #pragma unroll
                for (int nt = 0; nt < 4; nt++)
                    acc[nt] = __builtin_amdgcn_mfma_f32_16x16x32_bf16(ac[k2], bc[nt * 2 + k2], acc[nt], 0, 0, 0);
            #pragma unroll
            for (int i = 0; i < 2; i++) ac[i] = an[i];
            #pragma unroll
            for (int i = 0; i < 8; i++) bc[i] = bn[i];
        }
    } else {
        const u16* xb = (const u16*)x;
        const float* xf = (const float*)x;
        for (int kb = 0; kb < 16; kb++) {
            short8 af[2];
            #pragma unroll
            for (int k2 = 0; k2 < 2; k2++) {
                size_t src = (size_t)(g0r + l15) * CC + kb * 64 + k2 * 32 + quad * 8;
                if (isbf) {
                    af[k2] = *reinterpret_cast<const short8*>(xb + src);
                } else {
                    const float4* p = reinterpret_cast<const float4*>(xf + src);
                    float4 a0 = p[0], a1 = p[1];
                    short8 t;
                    t[0] = (short)f2bf(a0.x); t[1] = (short)f2bf(a0.y);
                    t[2] = (short)f2bf(a0.z); t[3] = (short)f2bf(a0.w);
                    t[4] = (short)f2bf(a1.x); t[5] = (short)f2bf(a1.y);
                    t[6] = (short)f2bf(a1.z); t[7] = (short)f2bf(a1.w);
                    af[k2] = t;
                }
            }
            #pragma unroll
            for (int k2 = 0; k2 < 2; k2++)
                #pragma unroll
                for (int nt = 0; nt < 4; nt++) {
                    short8 bf = *reinterpret_cast<const short8*>(
                        Wtp + bbase + (((size_t)(nt * 16 + kb) * 2 + k2) * 64 + lane) * 8);
                    acc[nt] = __builtin_amdgcn_mfma_f32_16x16x32_bf16(af[k2], bf, acc[nt], 0, 0, 0);
                }
        }
    }

    // Epilogue: 2 pairs of 16-col tiles through a 1KB LDS transpose (1-wave block).
    const float qscale = 0.18033688011112042f;   // log2(e)/8
    #pragma unroll
    for (int pair = 0; pair < 2; pair++) {
        __syncthreads();   // order tls reuse between pairs (1 wave: cheap)
        if (proj < 2) {
            float sc = (proj == 0) ? qscale : 1.f;
            #pragma unroll
            for (int e = 0; e < 2; e++) {
                int ntl = pair * 2 + e;
                #pragma unroll
                for (int r = 0; r < 4; r++)
                    tls[(quad * 4 + r) * 32 + e * 16 + l15] = f2bf(acc[ntl][r] * sc);
            }
            __syncthreads();
            int t = lane & 15, seg = lane >> 4;
            ushort4 d0 = *reinterpret_cast<const ushort4*>(&tls[t * 32 + seg * 8]);
            ushort4 d1 = *reinterpret_cast<const ushort4*>(&tls[t * 32 + seg * 8 + 4]);
            u16* dst = (proj == 0) ? qo : ko;
            u16* pd = dst + (size_t)(g0r + t) * HH + pair * 32 + seg * 8;
            *reinterpret_cast<ushort4*>(pd) = d0;
            *reinterpret_cast<ushort4*>(pd + 4) = d1;
        } else {
            // v: tile [c(32)][t(16)] -> vo[b][kt][h][64keys]
            #pragma unroll
            for (int e = 0; e < 2; e++) {
                int ntl = pair * 2 + e;
                #pragma unroll
                for (int r = 0; r < 4; r++)
                    tls[(e * 16 + l15) * 16 + quad * 4 + r] = f2bf(acc[ntl][r]);
            }
            __syncthreads();
            int c = lane & 31, tseg = lane >> 5;
            ushort4 d0 = *reinterpret_cast<const ushort4*>(&tls[c * 16 + tseg * 8]);
            ushort4 d1 = *reinterpret_cast<const ushort4*>(&tls[c * 16 + tseg * 8 + 4]);
            int b = rb >> 8;
            int kt = (g0r & 4095) >> 6;
            int toff = g0r & 63;
            u16* pd = vo + ((size_t)((b * 64 + kt) * 64 + pair * 32 + c)) * 64 + toff + tseg * 8;
            *reinterpret_cast<ushort4*>(pd) = d0;
            *reinterpret_cast<ushort4*>(pd + 4) = d1;
        }
    }
}

// ---------------- causal flash attention, 64 q-rows/block, split-K over 64-key tiles.
// vo is ktile-packed -> both K and V staging are contiguous 8KB reads.
__global__ __launch_bounds__(256) void attn(const u16* __restrict__ qp, const u16* __restrict__ kp,
                                            const u16* __restrict__ vp, float* __restrict__ acco,
                                            float* __restrict__ accl, void* __restrict__ outv,
                                            const int* __restrict__ flag, int nsplit) {
    __shared__ __align__(16) u16 kst[64 * 64];   // (key, h), swizzled
    __shared__ __align__(16) u16 vts[64 * 64];   // (h, key), swizzled
    __shared__ __align__(16) u16 pb[4][16 * 64]; // per-wave P
    const int isbf = *flag;
    const int tid = threadIdx.x;
    const int lane = tid & 63;
    const int w = tid >> 6;           // 0..3
    const int l15 = lane & 15;
    const int quad = lane >> 4;

    int u = blockIdx.x;
    int b, qt, ks;
    if (nsplit == 1) {
        b = u >> 6;
        int raw = u & 63;
        qt = (raw & 1) ? (63 - (raw >> 1)) : (raw >> 1);
        ks = 0;
    } else {
        int per = 64 * nsplit;
        b = u / per;
        int rem = u - b * per;
        qt = rem / nsplit;
        ks = rem - qt * nsplit;
    }
    int qbase = qt * 64;
    int diag = qt;
    int nkt = diag + 1;
    if (ks >= nkt) return;

    short8 aq[2];
    {
        const u16* qrow = qp + (size_t)(b * TT + qbase + w * 16 + l15) * HH;
        aq[0] = *reinterpret_cast<const short8*>(qrow + quad * 8);
        aq[1] = *reinterpret_cast<const short8*>(qrow + 32 + quad * 8);
    }

    f32x4 zero = {0.f, 0.f, 0.f, 0.f};
    f32x4 o[4];
    #pragma unroll
    for (int i = 0; i < 4; i++) o[i] = zero;
    f32x4 lsum = zero;

    for (int kt = ks; kt < nkt; kt += nsplit) {
        __syncthreads();              // previous iter's LDS reads done
        #pragma unroll
        for (int j = 0; j < 2; j++) {
            int cc = tid + j * 256;   // 512 chunks each, contiguous sources
            int row = cc >> 3, c8 = cc & 7;
            int dst = swz(row, c8);
            uint4 dk = *reinterpret_cast<const uint4*>(kp + (size_t)(b * TT + kt * 64) * HH + cc * 8);
            *reinterpret_cast<uint4*>(&kst[dst]) = dk;
            uint4 dv = *reinterpret_cast<const uint4*>(vp + ((size_t)(b * 64 + kt)) * 64 * 64 + cc * 8);
            *reinterpret_cast<uint4*>(&vts[dst]) = dv;
        }
        __syncthreads();              // staging visible
        // S = Q K^T (log2 domain via q pre-scale)
        f32x4 s[4];
        #pragma unroll
        for (int i = 0; i < 4; i++) s[i] = zero;
        #pragma unroll
        for (int k2 = 0; k2 < 2; k2++) {
            #pragma unroll
            for (int nt = 0; nt < 4; nt++) {
                short8 bf = *reinterpret_cast<const short8*>(&kst[swz(nt * 16 + l15, k2 * 4 + quad)]);
                s[nt] = __builtin_amdgcn_mfma_f32_16x16x32_bf16(aq[k2], bf, s[nt], 0, 0, 0);
            }
        }
        // p = exp2(s), causal mask on diagonal tile
        const int rg = qbase + w * 16 + quad * 4;
        const bool dm = (kt == diag);
        #pragma unroll
        for (int nt = 0; nt < 4; nt++) {
            int key = kt * 64 + nt * 16 + l15;
            #pragma unroll
            for (int r = 0; r < 4; r++) {
                float p = __builtin_amdgcn_exp2f(s[nt][r]);
                if (dm && key > rg + r) p = 0.f;
                s[nt][r] = p;
            }
        }
        #pragma unroll
        for (int nt = 0; nt < 4; nt++) lsum = lsum + s[nt];
        // P (C/D layout) -> per-wave LDS A-layout (same-wave RAW)
        #pragma unroll
        for (int nt = 0; nt < 4; nt++) {
            int chunk = nt * 2 + (l15 >> 3);
            int off = l15 & 7;
            #pragma unroll
            for (int r = 0; r < 4; r++) {
                int row = quad * 4 + r;
                pb[w][row * 64 + ((chunk ^ (row & 7)) << 3) + off] = f2bf(s[nt][r]);
            }
        }
        // O += P V
        #pragma unroll
        for (int k2 = 0; k2 < 2; k2++) {
            short8 ap = *reinterpret_cast<const short8*>(&pb[w][swz(l15, k2 * 4 + quad)]);
            #pragma unroll
            for (int nt = 0; nt < 4; nt++) {
                short8 bv = *reinterpret_cast<const short8*>(&vts[swz(nt * 16 + l15, k2 * 4 + quad)]);
                o[nt] = __builtin_amdgcn_mfma_f32_16x16x32_bf16(ap, bv, o[nt], 0, 0, 0);
            }
        }
    }

    #pragma unroll
    for (int d = 1; d < 16; d <<= 1) {
        f32x4 t;
        #pragma unroll
        for (int r = 0; r < 4; r++) t[r] = __shfl_xor(lsum[r], d);
        lsum = lsum + t;
    }
    const int g0 = b * TT + qbase + w * 16 + quad * 4;

    if (nsplit == 1) {
        f32x4 inv;
        #pragma unroll
        for (int r = 0; r < 4; r++) inv[r] = 1.0f / lsum[r];
        if (isbf) {
            u16* outp = (u16*)outv;
            #pragma unroll
            for (int nt = 0; nt < 4; nt++)
                #pragma unroll
                for (int r = 0; r < 4; r++)
                    outp[(size_t)(g0 + r) * HH + nt * 16 + l15] = f2bf(o[nt][r] * inv[r]);
        } else {
            float* outp = (float*)outv;
            #pragma unroll
            for (int nt = 0; nt < 4; nt++)
                #pragma unroll
                for (int r = 0; r < 4; r++)
                    outp[(size_t)(g0 + r) * HH + nt * 16 + l15] = o[nt][r] * inv[r];
        }
    } else {
        #pragma unroll
        for (int nt = 0; nt < 4; nt++)
            #pragma unroll
            for (int r = 0; r < 4; r++)
                atomicAdd(&acco[(size_t)(g0 + r) * HH + nt * 16 + l15], o[nt][r]);
        if (l15 == 0) {
            #pragma unroll
            for (int r = 0; r < 4; r++) atomicAdd(&accl[g0 + r], lsum[r]);
        }
    }
}

// ---------------- finalize: out = acco / accl
__global__ __launch_bounds__(256) void attn_finalize(const float* __restrict__ acco,
                                                     const float* __restrict__ accl,
                                                     void* __restrict__ outv,
                                                     const int* __restrict__ flag) {
    const int isbf = *flag;
    int i = blockIdx.x * blockDim.x + threadIdx.x;
    int row = i >> 4;
    float4 ov = reinterpret_cast<const float4*>(acco)[i];
    float inv = 1.0f / accl[row];
    if (isbf) {
        ushort4 s;
        s.x = f2bf(ov.x * inv); s.y = f2bf(ov.y * inv);
        s.z = f2bf(ov.z * inv); s.w = f2bf(ov.w * inv);
        reinterpret_cast<ushort4*>(outv)[i] = s;
    } else {
        float4 s = {ov.x * inv, ov.y * inv, ov.z * inv, ov.w * inv};
        reinterpret_cast<float4*>(outv)[i] = s;
    }
}

extern "C" void kernel_launch(void* const* d_in, const int* in_sizes, int n_in,
                              void* d_out, int out_size, void* d_ws, size_t ws_size,
                              hipStream_t stream) {
    const void* x  = d_in[0];
    const void* Wk = d_in[1];
    const void* Wq = d_in[2];
    const void* Wv = d_in[3];
    char* ws = (char*)d_ws;
    // ws: qo 0-2M | ko 2-4M | vo 4-6M | Wtp @6M(384K) | flag @6.75M | acco @7M(4M) | accl @11M(64K) | xp @12M(32M)
    u16* qo = (u16*)(ws);
    u16* ko = (u16*)(ws + (size_t)2 * 1024 * 1024);
    u16* vo = (u16*)(ws + (size_t)4 * 1024 * 1024);
    u16* Wtp = (u16*)(ws + (size_t)6 * 1024 * 1024);
    int* flag = (int*)(ws + (size_t)6 * 1024 * 1024 + 768 * 1024);
    float* acco = (float*)(ws + (size_t)7 * 1024 * 1024);
    float* accl = (float*)(ws + (size_t)11 * 1024 * 1024);
    u16* xp = (u16*)(ws + (size_t)12 * 1024 * 1024);

    const size_t need_split = (size_t)11 * 1024 * 1024 + 128 * 1024;
    const size_t need_xp = (size_t)44 * 1024 * 1024 + 128 * 1024;
    const int nsplit = (ws_size >= need_split) ? 4 : 1;
    const int use_xp = (ws_size >= need_xp) ? 1 : 0;

    detect_dtype<<<1, 64, 0, stream>>>((const u16*)x, flag);
    wt_transpose<<<(nsplit > 1 ? 448 : 192), 256, 0, stream>>>(Wk, Wq, Wv, Wtp, acco, flag);
    if (use_xp) xpack<<<2048, 256, 0, stream>>>(x, xp, flag);
    qkv_proj<<<3072, 64, 0, stream>>>(x, xp, Wtp, qo, ko, vo, flag, use_xp);
    if (nsplit > 1) {
        attn<<<BB * 64 * nsplit, 256, 0, stream>>>(qo, ko, vo, acco, accl, d_out, flag, nsplit);
        attn_finalize<<<(BB * TT * HH / 4) / 256, 256, 0, stream>>>(acco, accl, d_out, flag);
    } else {
        attn<<<BB * 64, 256, 0, stream>>>(qo, ko, vo, acco, accl, d_out, flag, 1);
    }
}

// Round 9
// 154.665 us; speedup vs baseline: 1.4039x; 1.1972x over previous
//
#include <hip/hip_runtime.h>

typedef __attribute__((ext_vector_type(8))) short short8;
typedef __attribute__((ext_vector_type(4))) float f32x4;
typedef unsigned short u16;

#define BB 4
#define TT 4096
#define CC 1024
#define HH 64

static __device__ __forceinline__ u16 f2bf(float f) {
    unsigned int u = __float_as_uint(f);
    unsigned int r = (u + 0x7FFFu + ((u >> 16) & 1u)) >> 16;  // RNE
    return (u16)r;
}

// attn LDS tile addressing: 64-u16 rows, 8 chunks of 8 u16; chunk XOR-swizzled by row&7.
static __device__ __forceinline__ int swz(int row, int chunk) {
    return row * 64 + ((chunk ^ (row & 7)) << 3);
}

// ---------------- dtype probe: flag=1 -> bf16 buffers, flag=0 -> f32 buffers.
__global__ void detect_dtype(const u16* __restrict__ xu, int* __restrict__ flag) {
    int lane = threadIdx.x;
    int cnt = 0;
    for (int i = lane; i < 1024; i += 64) {
        u16 u = xu[2 * i];
        int e = (u >> 7) & 0xFF;
        cnt += (e >= 100 && e <= 140) ? 1 : 0;
    }
    for (int d = 1; d < 64; d <<= 1) cnt += __shfl_xor(cnt, d);
    if (lane == 0) *flag = (cnt > 512) ? 1 : 0;
}

// ---------------- W -> Wtp packed B-fragment order; blocks >=192 zero acco/accl.
// Wtp 16B-chunk index: (((proj*4+nt)*16 + kb)*2 + k2)*64 + quad*16 + l15
// holding W[k = kb*64+k2*32+quad*8 .. +8][n = proj*64+nt*16+l15].
__global__ void wt_transpose(const void* __restrict__ Wk, const void* __restrict__ Wq,
                             const void* __restrict__ Wv, u16* __restrict__ Wtp,
                             float* __restrict__ accz, const int* __restrict__ flag) {
    if (blockIdx.x >= 192) {
        int zb = blockIdx.x - 192;
        const int n4 = (BB * TT * HH + BB * TT) / 4;   // acco + accl contiguous floats
        float4 z = {0.f, 0.f, 0.f, 0.f};
        for (int i = zb * 256 + threadIdx.x; i < n4; i += 256 * 256)
            reinterpret_cast<float4*>(accz)[i] = z;
        return;
    }
    const int isbf = *flag;
    int r = blockIdx.x;          // global output col 0..191
    int p = r >> 6;              // 0=q 1=k 2=v
    int n = r & 63;
    int nt = n >> 4, nl = n & 15;
    const void* W = (p == 0) ? Wq : (p == 1) ? Wk : Wv;
    int k0 = threadIdx.x * 4;    // 4 consecutive k per thread
    int kb = k0 >> 6, k2 = (k0 >> 5) & 1, quad = (k0 >> 3) & 3, half = (k0 >> 2) & 1;
    ushort4 v;
    if (isbf) {
        const u16* Wb = (const u16*)W;
        v.x = Wb[(k0 + 0) * HH + n]; v.y = Wb[(k0 + 1) * HH + n];
        v.z = Wb[(k0 + 2) * HH + n]; v.w = Wb[(k0 + 3) * HH + n];
    } else {
        const float* Wf = (const float*)W;
        v.x = f2bf(Wf[(k0 + 0) * HH + n]); v.y = f2bf(Wf[(k0 + 1) * HH + n]);
        v.z = f2bf(Wf[(k0 + 2) * HH + n]); v.w = f2bf(Wf[(k0 + 3) * HH + n]);
    }
    size_t off16 = ((size_t)((p * 4 + nt) * 16 + kb) * 2 + k2) * 64 + quad * 16 + nl;
    *reinterpret_cast<ushort4*>(Wtp + off16 * 8 + half * 4) = v;
}

// ---------------- QKV projection v4: fused LDS transpose, one barrier.
// 1024 blocks x 256 thr (4 waves). Block = 16 rows of x; the FULL K=1024 is staged
// into 32KB LDS with contiguous global reads, then the k-loop runs barrier-free:
// A-frags from LDS (swizzled), B-frags from L2-resident Wtp (contiguous 1KB/instr).
// Wave w computes col-tile w of each of q,k,v.
__global__ __launch_bounds__(256) void qkv_proj(const void* __restrict__ x,
                                                const u16* __restrict__ Wtp,
                                                u16* __restrict__ qo, u16* __restrict__ ko,
                                                u16* __restrict__ vo, const int* __restrict__ flag) {
    __shared__ __align__(16) u16 xs[16 * 1024];   // [row][k], 16B chunks swizzled by row&7
    __shared__ __align__(16) u16 tls[4][3][256];  // per-wave, per-proj 16x16 transpose tile
    const int isbf = *flag;
    const int tid = threadIdx.x;
    const int lane = tid & 63;
    const int w = tid >> 6;
    const int l15 = lane & 15;
    const int quad = lane >> 4;
    int phys = blockIdx.x;
    int rb = (phys & 7) * 128 + (phys >> 3);      // XCD-affine 16-row group, 0..1023
    const int g0r = rb * 16;

    // ---- stage 16 rows of x (contiguous reads; swizzled 16B-chunk writes)
    #pragma unroll
    for (int j = 0; j < 8; j++) {
        int c = tid + j * 256;                    // 2048 chunks: row = c>>7, ck = c&127
        int row = c >> 7, ck = c & 127;
        int dst = row * 1024 + ((ck ^ (row & 7)) << 3);
        if (isbf) {
            uint4 d = *reinterpret_cast<const uint4*>((const u16*)x + (size_t)(g0r + row) * CC + ck * 8);
            *reinterpret_cast<uint4*>(xs + dst) = d;
        } else {
            const float4* pf = reinterpret_cast<const float4*>((const float*)x + (size_t)(g0r + row) * CC + ck * 8);
            float4 a0 = pf[0], a1 = pf[1];
            ushort4 lo; lo.x = f2bf(a0.x); lo.y = f2bf(a0.y); lo.z = f2bf(a0.z); lo.w = f2bf(a0.w);
            ushort4 hi; hi.x = f2bf(a1.x); hi.y = f2bf(a1.y); hi.z = f2bf(a1.z); hi.w = f2bf(a1.w);
            *reinterpret_cast<ushort4*>(xs + dst) = lo;
            *reinterpret_cast<ushort4*>(xs + dst + 4) = hi;
        }
    }
    __syncthreads();                              // the ONLY block-wide barrier

    f32x4 zero = {0.f, 0.f, 0.f, 0.f};
    f32x4 acc[3];                                 // proj 0=q 1=k 2=v, col-tile w each
    #pragma unroll
    for (int i = 0; i < 3; i++) acc[i] = zero;

    for (int kb = 0; kb < 16; kb++) {
        #pragma unroll
        for (int k2 = 0; k2 < 2; k2++) {
            int ck = kb * 8 + k2 * 4 + quad;
            short8 af = *reinterpret_cast<const short8*>(xs + l15 * 1024 + ((ck ^ (l15 & 7)) << 3));
            #pragma unroll
            for (int p = 0; p < 3; p++) {
                short8 bf = *reinterpret_cast<const short8*>(
                    Wtp + ((((size_t)(p * 4 + w) * 16 + kb) * 2 + k2) * 64 + lane) * 8);
                acc[p] = __builtin_amdgcn_mfma_f32_16x16x32_bf16(af, bf, acc[p], 0, 0, 0);
            }
        }
    }

    // ---- epilogue: per-wave 16x16 LDS transpose, 8B coalesced stores
    const float qscale = 0.18033688011112042f;    // log2(e)/8
    #pragma unroll
    for (int p = 0; p < 3; p++) {
        if (p < 2) {
            float sc = (p == 0) ? qscale : 1.f;
            #pragma unroll
            for (int r = 0; r < 4; r++)           // [t(16)][c(16)]
                tls[w][p][(quad * 4 + r) * 16 + l15] = f2bf(acc[p][r] * sc);
        } else {
            #pragma unroll
            for (int r = 0; r < 4; r++)           // [c(16)][t(16)]
                tls[w][p][l15 * 16 + quad * 4 + r] = f2bf(acc[p][r]);
        }
    }
    // same-wave LDS RAW: compiler inserts lgkmcnt wait; no barrier needed
    #pragma unroll
    for (int p = 0; p < 2; p++) {                 // q, k: row-major (g0r+t)*64 + w*16+c
        int t = lane >> 2, seg = lane & 3;
        ushort4 d = *reinterpret_cast<const ushort4*>(&tls[w][p][t * 16 + seg * 4]);
        u16* dst = (p == 0) ? qo : ko;
        *reinterpret_cast<ushort4*>(dst + (size_t)(g0r + t) * HH + w * 16 + seg * 4) = d;
    }
    {                                             // v: vo[b][kt][h][64keys]
        int c = lane >> 2, seg = lane & 3;
        ushort4 d = *reinterpret_cast<const ushort4*>(&tls[w][2][c * 16 + seg * 4]);
        int b = rb >> 8;
        int kt = (g0r & 4095) >> 6;
        int toff = g0r & 63;
        *reinterpret_cast<ushort4*>(vo + ((size_t)((b * 64 + kt) * 64 + w * 16 + c)) * 64 + toff + seg * 4) = d;
    }
}

// ---------------- causal flash attention, 64 q-rows/block, split-K over 64-key tiles.
// vo is ktile-packed -> both K and V staging are contiguous 8KB reads.
__global__ __launch_bounds__(256) void attn(const u16* __restrict__ qp, const u16* __restrict__ kp,
                                            const u16* __restrict__ vp, float* __restrict__ acco,
                                            float* __restrict__ accl, void* __restrict__ outv,
                                            const int* __restrict__ flag, int nsplit) {
    __shared__ __align__(16) u16 kst[64 * 64];   // (key, h), swizzled
    __shared__ __align__(16) u16 vts[64 * 64];   // (h, key), swizzled
    __shared__ __align__(16) u16 pb[4][16 * 64]; // per-wave P
    const int isbf = *flag;
    const int tid = threadIdx.x;
    const int lane = tid & 63;
    const int w = tid >> 6;           // 0..3
    const int l15 = lane & 15;
    const int quad = lane >> 4;

    int u = blockIdx.x;
    int b, qt, ks;
    if (nsplit == 1) {
        b = u >> 6;
        int raw = u & 63;
        qt = (raw & 1) ? (63 - (raw >> 1)) : (raw >> 1);
        ks = 0;
    } else {
        int per = 64 * nsplit;
        b = u / per;
        int rem = u - b * per;
        qt = rem / nsplit;
        ks = rem - qt * nsplit;
    }
    int qbase = qt * 64;
    int diag = qt;
    int nkt = diag + 1;
    if (ks >= nkt) return;

    short8 aq[2];
    {
        const u16* qrow = qp + (size_t)(b * TT + qbase + w * 16 + l15) * HH;
        aq[0] = *reinterpret_cast<const short8*>(qrow + quad * 8);
        aq[1] = *reinterpret_cast<const short8*>(qrow + 32 + quad * 8);
    }

    f32x4 zero = {0.f, 0.f, 0.f, 0.f};
    f32x4 o[4];
    #pragma unroll
    for (int i = 0; i < 4; i++) o[i] = zero;
    f32x4 lsum = zero;

    for (int kt = ks; kt < nkt; kt += nsplit) {
        __syncthreads();              // previous iter's LDS reads done
        #pragma unroll
        for (int j = 0; j < 2; j++) {
            int cc = tid + j * 256;   // 512 chunks each, contiguous sources
            int row = cc >> 3, c8 = cc & 7;
            int dst = swz(row, c8);
            uint4 dk = *reinterpret_cast<const uint4*>(kp + (size_t)(b * TT + kt * 64) * HH + cc * 8);
            *reinterpret_cast<uint4*>(&kst[dst]) = dk;
            uint4 dv = *reinterpret_cast<const uint4*>(vp + ((size_t)(b * 64 + kt)) * 64 * 64 + cc * 8);
            *reinterpret_cast<uint4*>(&vts[dst]) = dv;
        }
        __syncthreads();              // staging visible
        // S = Q K^T (log2 domain via q pre-scale)
        f32x4 s[4];
        #pragma unroll
        for (int i = 0; i < 4; i++) s[i] = zero;
        #pragma unroll
        for (int k2 = 0; k2 < 2; k2++) {
            #pragma unroll
            for (int nt = 0; nt < 4; nt++) {
                short8 bf = *reinterpret_cast<const short8*>(&kst[swz(nt * 16 + l15, k2 * 4 + quad)]);
                s[nt] = __builtin_amdgcn_mfma_f32_16x16x32_bf16(aq[k2], bf, s[nt], 0, 0, 0);
            }
        }
        // p = exp2(s), causal mask on diagonal tile
        const int rg = qbase + w * 16 + quad * 4;
        const bool dm = (kt == diag);
        #pragma unroll
        for (int nt = 0; nt < 4; nt++) {
            int key = kt * 64 + nt * 16 + l15;
            #pragma unroll
            for (int r = 0; r < 4; r++) {
                float p = __builtin_amdgcn_exp2f(s[nt][r]);
                if (dm && key > rg + r) p = 0.f;
                s[nt][r] = p;
            }
        }
        #pragma unroll
        for (int nt = 0; nt < 4; nt++) lsum = lsum + s[nt];
        // P (C/D layout) -> per-wave LDS A-layout (same-wave RAW)
        #pragma unroll
        for (int nt = 0; nt < 4; nt++) {
            int chunk = nt * 2 + (l15 >> 3);
            int off = l15 & 7;
            #pragma unroll
            for (int r = 0; r < 4; r++) {
                int row = quad * 4 + r;
                pb[w][row * 64 + ((chunk ^ (row & 7)) << 3) + off] = f2bf(s[nt][r]);
            }
        }
        // O += P V
        #pragma unroll
        for (int k2 = 0; k2 < 2; k2++) {
            short8 ap = *reinterpret_cast<const short8*>(&pb[w][swz(l15, k2 * 4 + quad)]);
            #pragma unroll
            for (int nt = 0; nt < 4; nt++) {
                short8 bv = *reinterpret_cast<const short8*>(&vts[swz(nt * 16 + l15, k2 * 4 + quad)]);
                o[nt] = __builtin_amdgcn_mfma_f32_16x16x32_bf16(ap, bv, o[nt], 0, 0, 0);
            }
        }
    }

    #pragma unroll
    for (int d = 1; d < 16; d <<= 1) {
        f32x4 t;
        #pragma unroll
        for (int r = 0; r < 4; r++) t[r] = __shfl_xor(lsum[r], d);
        lsum = lsum + t;
    }
    const int g0 = b * TT + qbase + w * 16 + quad * 4;

    if (nsplit == 1) {
        f32x4 inv;
        #pragma unroll
        for (int r = 0; r < 4; r++) inv[r] = 1.0f / lsum[r];
        if (isbf) {
            u16* outp = (u16*)outv;
            #pragma unroll
            for (int nt = 0; nt < 4; nt++)
                #pragma unroll
                for (int r = 0; r < 4; r++)
                    outp[(size_t)(g0 + r) * HH + nt * 16 + l15] = f2bf(o[nt][r] * inv[r]);
        } else {
            float* outp = (float*)outv;
            #pragma unroll
            for (int nt = 0; nt < 4; nt++)
                #pragma unroll
                for (int r = 0; r < 4; r++)
                    outp[(size_t)(g0 + r) * HH + nt * 16 + l15] = o[nt][r] * inv[r];
        }
    } else {
        #pragma unroll
        for (int nt = 0; nt < 4; nt++)
            #pragma unroll
            for (int r = 0; r < 4; r++)
                atomicAdd(&acco[(size_t)(g0 + r) * HH + nt * 16 + l15], o[nt][r]);
        if (l15 == 0) {
            #pragma unroll
            for (int r = 0; r < 4; r++) atomicAdd(&accl[g0 + r], lsum[r]);
        }
    }
}

// ---------------- finalize: out = acco / accl
__global__ __launch_bounds__(256) void attn_finalize(const float* __restrict__ acco,
                                                     const float* __restrict__ accl,
                                                     void* __restrict__ outv,
                                                     const int* __restrict__ flag) {
    const int isbf = *flag;
    int i = blockIdx.x * blockDim.x + threadIdx.x;
    int row = i >> 4;
    float4 ov = reinterpret_cast<const float4*>(acco)[i];
    float inv = 1.0f / accl[row];
    if (isbf) {
        ushort4 s;
        s.x = f2bf(ov.x * inv); s.y = f2bf(ov.y * inv);
        s.z = f2bf(ov.z * inv); s.w = f2bf(ov.w * inv);
        reinterpret_cast<ushort4*>(outv)[i] = s;
    } else {
        float4 s = {ov.x * inv, ov.y * inv, ov.z * inv, ov.w * inv};
        reinterpret_cast<float4*>(outv)[i] = s;
    }
}

extern "C" void kernel_launch(void* const* d_in, const int* in_sizes, int n_in,
                              void* d_out, int out_size, void* d_ws, size_t ws_size,
                              hipStream_t stream) {
    const void* x  = d_in[0];
    const void* Wk = d_in[1];
    const void* Wq = d_in[2];
    const void* Wv = d_in[3];
    char* ws = (char*)d_ws;
    // ws: qo 0-2M | ko 2-4M | vo 4-6M | Wtp @6M(384K) | flag @6.75M | acco @7M(4M) | accl @11M(64K)
    u16* qo = (u16*)(ws);
    u16* ko = (u16*)(ws + (size_t)2 * 1024 * 1024);
    u16* vo = (u16*)(ws + (size_t)4 * 1024 * 1024);
    u16* Wtp = (u16*)(ws + (size_t)6 * 1024 * 1024);
    int* flag = (int*)(ws + (size_t)6 * 1024 * 1024 + 768 * 1024);
    float* acco = (float*)(ws + (size_t)7 * 1024 * 1024);
    float* accl = (float*)(ws + (size_t)11 * 1024 * 1024);

    const size_t need_split = (size_t)11 * 1024 * 1024 + 128 * 1024;
    const int nsplit = (ws_size >= need_split) ? 4 : 1;

    detect_dtype<<<1, 64, 0, stream>>>((const u16*)x, flag);
    wt_transpose<<<(nsplit > 1 ? 448 : 192), 256, 0, stream>>>(Wk, Wq, Wv, Wtp, acco, flag);
    qkv_proj<<<1024, 256, 0, stream>>>(x, Wtp, qo, ko, vo, flag);
    if (nsplit > 1) {
        attn<<<BB * 64 * nsplit, 256, 0, stream>>>(qo, ko, vo, acco, accl, d_out, flag, nsplit);
        attn_finalize<<<(BB * TT * HH / 4) / 256, 256, 0, stream>>>(acco, accl, d_out, flag);
    } else {
        attn<<<BB * 64, 256, 0, stream>>>(qo, ko, vo, acco, accl, d_out, flag, 1);
    }
}